// Round 5
// baseline (281.093 us; speedup 1.0000x reference)
//
#include <hip/hip_runtime.h>

// AvgPoolVectorsPerWSI: x [2048, 512, 7, 7] f32, idx [2048] i32 in [0,64)
// out [64, 512, 1, 1] f32 = segment_mean over samples of spatial-sum / 49.

#define N_SAMPLES 2048
#define M_CHANNELS 512
#define SPATIAL 49
#define GROUPS 64
#define CHUNK_CH 64                           // channels per chunk (1/lane)
#define CHUNK_FLOATS (CHUNK_CH * SPATIAL)     // 3136 floats = 12544 B
#define TOTAL_CHUNKS (N_SAMPLES * (M_CHANNELS / CHUNK_CH))  // 16384
#define GRID 1536                             // 6 one-wave blocks per CU

typedef __attribute__((address_space(1))) const void global_void;
typedef __attribute__((address_space(3))) void lds_void;

// Issue 13 global_load_lds (12 full-wave 1-KiB + one 16-lane tail) for one
// chunk. Exactly 13 vmcnt ops per call — the counted-wait invariant relies
// on this.
__device__ __forceinline__ void stage_chunk(const float* __restrict__ src,
                                            float* dst, int lane) {
#pragma unroll
  for (int k = 0; k < 12; ++k) {
    __builtin_amdgcn_global_load_lds(
        (global_void*)(src + (size_t)(k * 64 + lane) * 4),
        (lds_void*)(dst + k * 256), 16, 0, 0);
  }
  if (lane < 16) {  // tail: float4 768..783
    __builtin_amdgcn_global_load_lds(
        (global_void*)(src + (size_t)(768 + lane) * 4),
        (lds_void*)(dst + 3072), 16, 0, 0);
  }
}

// Reduce one staged chunk: lane owns one channel = 49 consecutive floats at
// lane*49 (stride-49 words -> bank 17*lane mod 32 -> 2 lanes/bank, free).
// Pairwise tree keeps the fp-add dependence chain at ~6 deep (no fast-math
// reassociation needed). One atomicAdd per lane.
__device__ __forceinline__ void reduce_chunk(const float* ldsbuf, int lane,
                                             const int* __restrict__ idx,
                                             int chunk,
                                             float* __restrict__ accum) {
  const float* row = ldsbuf + lane * SPATIAL;
  float v[SPATIAL];
#pragma unroll
  for (int i = 0; i < SPATIAL; ++i) v[i] = row[i];
#pragma unroll
  for (int s = 1; s < 64; s *= 2)
#pragma unroll
    for (int i = 0; i + s < SPATIAL; i += 2 * s) v[i] += v[i + s];
  const int g = idx[chunk >> 3];  // wave-uniform
  atomicAdd(accum + (size_t)g * M_CHANNELS + (chunk & 7) * CHUNK_CH + lane,
            v[0]);
}

// Persistent 1-wave blocks, double-buffered LDS, counted vmcnt (T3/T4):
//   stage(c0, buf0)
//   loop: stage(c+GRID, buf^1); s_waitcnt vmcnt(13); reduce(buf, c); swap
// vmcnt(13) is exact: the 13 just-issued loads are the ONLY ops allowed
// outstanding; in-order decrement drains the older chunk's loads plus the
// previous iteration's atomic/idx-load. Never vmcnt(0) in the loop.
// LDS 2*12544 B/wave, 6 waves/CU -> whole grid resident, no turnover,
// every wave streams continuously.
__global__ __launch_bounds__(64) void scatter_kernel(
    const float* __restrict__ x, const int* __restrict__ idx,
    float* __restrict__ accum) {
  __shared__ float buf[2 * CHUNK_FLOATS];
  const int lane = threadIdx.x;
  int c = blockIdx.x;

  stage_chunk(x + (size_t)c * CHUNK_FLOATS, buf, lane);
  int cur = 0;
  for (; c + GRID < TOTAL_CHUNKS; c += GRID) {
    stage_chunk(x + (size_t)(c + GRID) * CHUNK_FLOATS,
                buf + (cur ^ 1) * CHUNK_FLOATS, lane);
    __builtin_amdgcn_sched_barrier(0);
    asm volatile("s_waitcnt vmcnt(13)" ::: "memory");
    __builtin_amdgcn_sched_barrier(0);  // rule #18: pin ds_read below wait
    reduce_chunk(buf + cur * CHUNK_FLOATS, lane, idx, c, accum);
    cur ^= 1;
  }
  asm volatile("s_waitcnt vmcnt(0)" ::: "memory");
  __builtin_amdgcn_sched_barrier(0);
  reduce_chunk(buf + cur * CHUNK_FLOATS, lane, idx, c, accum);
}

// One block per group g, 512 threads (one per channel). Recompute the group
// count from idx (tiny, L2-hot), then scale the accumulated sum in place.
__global__ __launch_bounds__(512) void finalize_kernel(
    const int* __restrict__ idx, float* __restrict__ out) {
  const int g = blockIdx.x;
  const int t = threadIdx.x;

  __shared__ int cnt;
  if (t == 0) cnt = 0;
  __syncthreads();

  int local = 0;
#pragma unroll
  for (int i = 0; i < N_SAMPLES / 512; ++i)
    local += (idx[t + i * 512] == g) ? 1 : 0;
  atomicAdd(&cnt, local);
  __syncthreads();

  // count==0 -> inv=inf, 0*inf=NaN, matching reference 0/0.
  const float inv = 1.0f / ((float)cnt * (float)SPATIAL);
  out[(size_t)g * M_CHANNELS + t] *= inv;
}

extern "C" void kernel_launch(void* const* d_in, const int* in_sizes, int n_in,
                              void* d_out, int out_size, void* d_ws, size_t ws_size,
                              hipStream_t stream) {
  const float* x = (const float*)d_in[0];
  const int* idx = (const int*)d_in[1];
  float* out = (float*)d_out;

  // Zero the accumulator (harness poisons d_out with 0xAA each call).
  hipMemsetAsync(out, 0, (size_t)GROUPS * M_CHANNELS * sizeof(float), stream);

  scatter_kernel<<<GRID, 64, 0, stream>>>(x, idx, out);
  finalize_kernel<<<GROUPS, M_CHANNELS, 0, stream>>>(idx, out);
}